// Round 1
// 3235.590 us; speedup vs baseline: 1.5565x; 1.5565x over previous
//
#include <hip/hip_runtime.h>
#include <math.h>

// B=8, C=128, H=128, W=128, D_INNER=256, D_STATE=64, HEADDIM=32, NHEADS=8,
// D_CONV=4, GN_GROUPS=8, D_XBC=384, D_INPROJ=648.
// Inputs f32 (probed via gn_g word0). OUTPUT IS F32 (reference output dtype).
// d_out = [out_2d: 16,777,216 f32][offset: 131,072 f32].
// h1 (f32) is staged in d_out's out_2d region (written by dwconv, read by gn_off,
// later fully overwritten by gemm2).

__device__ __forceinline__ float b2f(unsigned short u) {
  return __uint_as_float(((unsigned int)u) << 16);
}
__device__ __forceinline__ unsigned short f2b(float f) {
  unsigned int u = __float_as_uint(f);
  unsigned int r = (u + 0x7FFFu + ((u >> 16) & 1u)) >> 16;  // RNE
  return (unsigned short)r;
}
__device__ __forceinline__ bool in_is_f32(const void* gng) {
  return ((const unsigned int*)gng)[0] == 0x3F800000u;
}

#define P_DWW 0
#define P_CW 3200
#define P_CB 4736
#define P_GNG 5120
#define P_GNB 5248
#define P_PWW 5376
#define P_PWB 5504
#define P_DTB 5505
#define P_ALOG 5513
#define P_DSKIP 5521
#define P_NG 5529

__global__ void k_prep_params(const void* dww, const void* cw, const void* cb,
                              const void* gng, const void* gnb, const void* pww,
                              const void* pwb, const void* dtbias, const void* alog,
                              const void* dskip, const void* ng, float* __restrict__ P,
                              float* __restrict__ gst) {
  bool f = in_is_f32(gng);
  int tid = threadIdx.x;
  if (tid < 128) gst[tid] = 0.f;
  auto cvt = [&](const void* src, int n, int off) {
    for (int i = tid; i < n; i += 256)
      P[off + i] = f ? ((const float*)src)[i] : b2f(((const unsigned short*)src)[i]);
  };
  cvt(dww, 3200, P_DWW);
  cvt(cw, 1536, P_CW);
  cvt(cb, 384, P_CB);
  cvt(gng, 128, P_GNG);
  cvt(gnb, 128, P_GNB);
  cvt(pww, 128, P_PWW);
  cvt(pwb, 1, P_PWB);
  cvt(dtbias, 8, P_DTB);
  cvt(alog, 8, P_ALOG);
  cvt(dskip, 8, P_DSKIP);
  cvt(ng, 256, P_NG);
}

__global__ void k_prep_w(const void* wproj, const void* outw, const void* gng,
                         float* __restrict__ wprojf, float* __restrict__ outwf) {
  bool f = in_is_f32(gng);
  int stride = gridDim.x * blockDim.x;
  for (int i = blockIdx.x * blockDim.x + threadIdx.x; i < 82944; i += stride)
    wprojf[i] = f ? ((const float*)wproj)[i] : b2f(((const unsigned short*)wproj)[i]);
  for (int i = blockIdx.x * blockDim.x + threadIdx.x; i < 32768; i += stride)
    outwf[i] = f ? ((const float*)outw)[i] : b2f(((const unsigned short*)outw)[i]);
}

// ---------------- K1: depthwise 5x5 conv (SAME, zero pad) + group stats ----------
// x staged in LDS as bf16 (f32 tile would exceed 64KB static LDS); h1 out f32.
__global__ __launch_bounds__(256) void k_dwconv(const void* __restrict__ x,
                                                const void* __restrict__ gng,
                                                const float* __restrict__ P,
                                                float* __restrict__ h1,
                                                float* __restrict__ gst) {
  int bc = blockIdx.x;
  int b = bc >> 7, c = bc & 127;
  bool f32x = in_is_f32(gng);
  __shared__ unsigned short t[132 * 132];
  __shared__ float red[8];
  for (int i = threadIdx.x; i < 132 * 132; i += 256) t[i] = 0;
  __syncthreads();
  const float* xf = (const float*)x + (size_t)bc * 16384;
  const unsigned short* xb = (const unsigned short*)x + (size_t)bc * 16384;
  for (int i = threadIdx.x; i < 16384; i += 256) {
    int y = i >> 7, xw = i & 127;
    t[(y + 2) * 132 + xw + 2] = f32x ? f2b(xf[i]) : xb[i];
  }
  float w[25];
#pragma unroll
  for (int k = 0; k < 25; ++k) w[k] = P[P_DWW + c * 25 + k];
  __syncthreads();
  float s = 0.f, sq = 0.f;
  for (int i = threadIdx.x; i < 16384; i += 256) {
    int y = i >> 7, xw = i & 127;
    float acc = 0.f;
#pragma unroll
    for (int ky = 0; ky < 5; ++ky)
#pragma unroll
      for (int kx = 0; kx < 5; ++kx)
        acc += w[ky * 5 + kx] * b2f(t[(y + ky) * 132 + xw + kx]);
    h1[(size_t)bc * 16384 + i] = acc;
    s += acc; sq += acc * acc;
  }
  for (int o = 32; o; o >>= 1) { s += __shfl_down(s, o, 64); sq += __shfl_down(sq, o, 64); }
  int wv = threadIdx.x >> 6;
  if ((threadIdx.x & 63) == 0) { red[wv] = s; red[4 + wv] = sq; }
  __syncthreads();
  if (threadIdx.x == 0) {
    float ts = red[0] + red[1] + red[2] + red[3];
    float tq = red[4] + red[5] + red[6] + red[7];
    int g = (b << 3) + (c >> 4);
    atomicAdd(&gst[g * 2], ts);
    atomicAdd(&gst[g * 2 + 1], tq);
  }
}

__global__ void k_stats(const float* __restrict__ gst, float* __restrict__ mr) {
  int g = threadIdx.x;
  if (g < 64) {
    const float invN = 1.f / 262144.f;
    float mean = gst[g * 2] * invN;
    float var = gst[g * 2 + 1] * invN - mean * mean;
    mr[g * 2] = mean;
    mr[g * 2 + 1] = rsqrtf(var + 1e-5f);
  }
}

// ---------------- K3: GN + exact GELU + 1x1 conv + tanh*8 -> offset (f32 out) ----
__global__ __launch_bounds__(128) void k_gn_off(const float* __restrict__ h1,
                                                const float* __restrict__ mr,
                                                const float* __restrict__ P,
                                                float* __restrict__ offf,
                                                float* __restrict__ dout) {
  int bh = blockIdx.x;
  int b = bh >> 7, h = bh & 127;
  int w = threadIdx.x;
  float acc = 0.f;
  for (int c = 0; c < 128; ++c) {
    float v = h1[(((size_t)(b * 128 + c)) * 128 + h) * 128 + w];
    int g = b * 8 + (c >> 4);
    float nv = (v - mr[g * 2]) * mr[g * 2 + 1] * P[P_GNG + c] + P[P_GNB + c];
    float ge = 0.5f * nv * (1.f + erff(nv * 0.70710678118f));
    acc += ge * P[P_PWW + c];
  }
  float off = acc + P[P_PWB];
  float ofv = tanhf(off) * 8.0f;
  offf[bh * 128 + w] = ofv;
  dout[16777216 + bh * 128 + w] = ofv;
}

// ---------------- K4: y-only grid sample + transpose -> seq f32 (l,c) ------------
__global__ __launch_bounds__(128) void k_deform(const void* __restrict__ x,
                                                const void* __restrict__ gng,
                                                const float* __restrict__ offf,
                                                float* __restrict__ seqc,
                                                int s0) {
  int bh = s0 + blockIdx.x;
  int b = bh >> 7, h = bh & 127;
  int w = threadIdx.x;
  bool f32x = in_is_f32(gng);
  __shared__ float t[128 * 130];
  float ofv = offf[bh * 128 + w];
  float gy = -1.f + (2.f / 127.f) * (float)h + ofv * (2.f / 127.f);
  gy = fminf(fmaxf(gy, -1.f), 1.f);
  float py = (gy + 1.f) * 0.5f * 127.f;
  py = fminf(fmaxf(py, 0.f), 127.f);
  float y0f = floorf(py);
  float wy = py - y0f;
  int y0 = (int)y0f;
  int y1 = min(y0 + 1, 127);
  const float* xfb = (const float*)x + (size_t)b * 128 * 16384;
  const unsigned short* xbb = (const unsigned short*)x + (size_t)b * 128 * 16384;
  for (int c = 0; c < 128; ++c) {
    size_t o0 = (size_t)c * 16384 + y0 * 128 + w;
    size_t o1 = (size_t)c * 16384 + y1 * 128 + w;
    float v0, v1;
    if (f32x) { v0 = xfb[o0]; v1 = xfb[o1]; }
    else      { v0 = b2f(xbb[o0]); v1 = b2f(xbb[o1]); }
    t[c * 130 + w] = v0 + wy * (v1 - v0);
  }
  __syncthreads();
  int c = threadIdx.x;
  float* sp = seqc + (size_t)blockIdx.x * 16384;
  for (int l = 0; l < 128; ++l) sp[l * 128 + c] = t[c * 130 + l];
}

// ---------------- G1: zxbcdt = seq @ wproj^T — LDS-tiled VALU --------------------
__global__ __launch_bounds__(256) void k_gemm1(const float* __restrict__ seqp,
                                               const float* __restrict__ wproj,
                                               const float* __restrict__ P,
                                               float* __restrict__ z,
                                               float* __restrict__ xbc,
                                               float* __restrict__ dtb) {
  __shared__ float As[16 * 129];
  __shared__ float Bs[16 * 129];
  int m0 = blockIdx.x * 16;
  int e0 = blockIdx.y * 16;
  for (int i = threadIdx.x; i < 2048; i += 256) {
    int row = i >> 7, k = i & 127;
    As[row * 129 + k] = seqp[(size_t)(m0 + row) * 128 + k];
    int e = e0 + row;
    Bs[row * 129 + k] = (e < 648) ? wproj[(size_t)e * 128 + k] : 0.f;
  }
  __syncthreads();
  int tx = threadIdx.x & 15;
  int ty = threadIdx.x >> 4;
  float acc = 0.f;
#pragma unroll 8
  for (int k = 0; k < 128; ++k) acc += As[ty * 129 + k] * Bs[tx * 129 + k];
  int m = m0 + ty;
  int e = e0 + tx;
  if (e < 256) {
    z[(size_t)m * 256 + e] = acc;
  } else if (e < 640) {
    xbc[(size_t)m * 384 + (e - 256)] = acc;
  } else if (e < 648) {
    float dv = acc + P[P_DTB + e - 640];
    float sp = (dv > 20.f) ? dv : log1pf(__expf(dv));
    dtb[(size_t)m * 8 + (e - 640)] = sp;
  }
}

// ---------------- K5: causal conv1d + SiLU, out-of-place -------------------------
__global__ __launch_bounds__(256) void k_conv1d_v2(const float* __restrict__ xbc,
                                                   float* __restrict__ pc,
                                                   const float* __restrict__ P) {
  const float* in = xbc + (size_t)blockIdx.x * 49152;   // 128*384
  float* out = pc + (size_t)blockIdx.x * 49152;
  for (int e = threadIdx.x; e < 384; e += 256) {
    float w0 = P[P_CW + e * 4 + 0], w1 = P[P_CW + e * 4 + 1];
    float w2 = P[P_CW + e * 4 + 2], w3 = P[P_CW + e * 4 + 3];
    float bb = P[P_CB + e];
    float x0 = 0.f, x1 = 0.f, x2 = 0.f;
    for (int l = 0; l < 128; ++l) {
      float x3 = in[l * 384 + e];
      float a = bb + w0 * x0 + w1 * x1 + w2 * x2 + w3 * x3;
      out[l * 384 + e] = a / (1.f + __expf(-a));
      x0 = x1; x1 = x2; x2 = x3;
    }
  }
}

// ---------------- K6: selective scan v3. block=seq; thread=(head,d) --------------
// v2 bug: "#pragma unroll 16" left h[s] runtime-indexed -> h[64] spilled to
// scratch (VGPR_Count=20, WRITE_SIZE ~889MB/dispatch = state round-trip every
// timestep). v3: FULL unroll (h in VGPRs), no LDS / no barriers (B,C are
// wave-uniform -> direct uniform float4 global loads, L1 broadcast), and the
// 64-long acc dependency chain split into 4 partials.
__global__ __launch_bounds__(256) void k_scan_v3(const float* __restrict__ pc,
                                                 const float* __restrict__ dtb,
                                                 const float* __restrict__ P,
                                                 float* __restrict__ ys) {
  int seq = blockIdx.x;
  int head = threadIdx.x >> 5;    // 0..7
  int d = threadIdx.x & 31;       // 0..31
  float A = -__expf(P[P_ALOG + head]);
  float Dk = P[P_DSKIP + head];
  float h[64];
#pragma unroll
  for (int s = 0; s < 64; ++s) h[s] = 0.f;
  const float* base = pc + (size_t)seq * 49152;
  const float* dtp = dtb + (size_t)seq * 1024;
  float* yp = ys + (size_t)seq * 32768;
  for (int l = 0; l < 128; ++l) {
    const float* rb = base + l * 384;
    float dt = dtp[l * 8 + head];
    float xv = rb[head * 32 + d];
    float dA = __expf(dt * A);
    float coef = dt * xv;
    const float4* Bv = (const float4*)(rb + 256);  // 16B-aligned, wave-uniform
    const float4* Cv = (const float4*)(rb + 320);
    float a0 = 0.f, a1 = 0.f, a2 = 0.f, a3 = 0.f;
#pragma unroll
    for (int q = 0; q < 16; ++q) {
      float4 bq = Bv[q];
      float4 cq = Cv[q];
      h[q * 4 + 0] = h[q * 4 + 0] * dA + coef * bq.x;  a0 += h[q * 4 + 0] * cq.x;
      h[q * 4 + 1] = h[q * 4 + 1] * dA + coef * bq.y;  a1 += h[q * 4 + 1] * cq.y;
      h[q * 4 + 2] = h[q * 4 + 2] * dA + coef * bq.z;  a2 += h[q * 4 + 2] * cq.z;
      h[q * 4 + 3] = h[q * 4 + 3] * dA + coef * bq.w;  a3 += h[q * 4 + 3] * cq.w;
    }
    yp[l * 256 + head * 32 + d] = ((a0 + a1) + (a2 + a3)) + Dk * xv;
  }
}

// ---------------- K7: gate + RMS norm, block per token ---------------------------
__global__ __launch_bounds__(256) void k_gate_v2(const float* __restrict__ ys,
                                                 const float* __restrict__ z,
                                                 const float* __restrict__ P,
                                                 float* __restrict__ ynorm) {
  int l = blockIdx.x;
  int e = threadIdx.x;
  __shared__ float red[4];
  float yv = ys[(size_t)l * 256 + e];
  float zv = z[(size_t)l * 256 + e];
  float g = zv / (1.f + __expf(-zv));
  float y = yv * g;
  float ss = y * y;
  for (int o = 32; o; o >>= 1) ss += __shfl_down(ss, o, 64);
  if ((threadIdx.x & 63) == 0) red[threadIdx.x >> 6] = ss;
  __syncthreads();
  float tot = red[0] + red[1] + red[2] + red[3];
  float r = rsqrtf(tot * (1.f / 256.f) + 1e-5f);
  ynorm[(size_t)l * 256 + e] = y * r * P[P_NG + e];
}

// ---------------- G2: out GEMM — LDS-tiled VALU, f32 NCHW store ------------------
__global__ __launch_bounds__(256) void k_gemm2(const float* __restrict__ ynorm,
                                               const float* __restrict__ outw,
                                               float* __restrict__ dout,
                                               int tok0) {
  __shared__ float As[16 * 257];
  __shared__ float Bs[16 * 257];
  int c0 = blockIdx.x * 16;
  int t0 = blockIdx.y * 16;
  for (int i = threadIdx.x; i < 4096; i += 256) {
    int row = i >> 8, k = i & 255;
    As[row * 257 + k] = outw[(size_t)(c0 + row) * 256 + k];
    Bs[row * 257 + k] = ynorm[(size_t)(t0 + row) * 256 + k];
  }
  __syncthreads();
  int tx = threadIdx.x & 15;
  int ty = threadIdx.x >> 4;
  float acc = 0.f;
#pragma unroll 8
  for (int k = 0; k < 256; ++k) acc += As[ty * 257 + k] * Bs[tx * 257 + k];
  int cc = c0 + ty;
  int l = tok0 + t0 + tx;
  int b = l >> 14, rem = l & 16383;
  int hh = rem >> 7, ww = rem & 127;
  dout[(((size_t)(b * 128 + cc) * 128 + hh) * 128 + ww)] = acc;
}

extern "C" void kernel_launch(void* const* d_in, const int* in_sizes, int n_in,
                              void* d_out, int out_size, void* d_ws, size_t ws_size,
                              hipStream_t stream) {
  const void* x      = d_in[0];
  const void* dww    = d_in[1];
  const void* gng    = d_in[2];
  const void* gnb    = d_in[3];
  const void* pww    = d_in[4];
  const void* pwb    = d_in[5];
  const void* wproj  = d_in[6];
  const void* cw     = d_in[7];
  const void* cb     = d_in[8];
  const void* dtbias = d_in[9];
  const void* alog   = d_in[10];
  const void* dskip  = d_in[11];
  const void* ng     = d_in[12];
  const void* outw   = d_in[13];
  float* out = (float*)d_out;

  // ws layout (bytes):
  //   0        gst (512)
  //   4096     mr (512)
  //   8192     P (32768)        -> 40960
  //   40960    wprojf (331776)  -> 372736
  //   372736   outwf (131072)   -> 503808
  //   503808   offf (524288)    -> 1028096
  //   1028096  chunk buffers
  char* ws = (char*)d_ws;
  float* gst    = (float*)(ws + 0);
  float* mr     = (float*)(ws + 4096);
  float* P      = (float*)(ws + 8192);
  float* wprojf = (float*)(ws + 40960);
  float* outwf  = (float*)(ws + 372736);
  float* offf   = (float*)(ws + 503808);
  char* cbase   = ws + 1028096;

  // h1 (f32, 67,108,864 B) lives in d_out's out_2d region.
  float* h1f = out;

  // Per-sequence chunk bytes: seq 65536 + z 131072 + xbc 196608 + pc 196608
  //                         + dtb 4096 + ys 131072 + ynorm 131072 = 856064.
  const int opts[11] = {1024, 512, 256, 128, 64, 32, 16, 8, 4, 2, 1};
  int CH = 1;
  for (int i = 0; i < 11; ++i) {
    if (1028096ull + (unsigned long long)opts[i] * 856064ull <= (unsigned long long)ws_size) {
      CH = opts[i];
      break;
    }
  }
  int NC = 1024 / CH;

  float* seqf = (float*)(cbase);
  float* zf   = (float*)(cbase + (size_t)CH * 65536);
  float* xbcf = (float*)(cbase + (size_t)CH * 196608);
  float* pcf  = (float*)(cbase + (size_t)CH * 393216);
  float* dtbf = (float*)(cbase + (size_t)CH * 589824);
  float* ysf  = (float*)(cbase + (size_t)CH * 593920);
  float* ynf  = (float*)(cbase + (size_t)CH * 724992);

  k_prep_params<<<1, 256, 0, stream>>>(dww, cw, cb, gng, gnb, pww, pwb, dtbias,
                                       alog, dskip, ng, P, gst);
  k_prep_w<<<128, 256, 0, stream>>>(wproj, outw, gng, wprojf, outwf);
  k_dwconv<<<1024, 256, 0, stream>>>(x, gng, P, h1f, gst);
  k_stats<<<1, 64, 0, stream>>>(gst, mr);
  k_gn_off<<<1024, 128, 0, stream>>>(h1f, mr, P, offf, out);

  for (int c = 0; c < NC; ++c) {
    int s0 = c * CH;
    k_deform<<<CH, 128, 0, stream>>>(x, gng, offf, seqf, s0);
    k_gemm1<<<dim3(CH * 8, 41), 256, 0, stream>>>(seqf, wprojf, P, zf, xbcf, dtbf);
    k_conv1d_v2<<<CH, 256, 0, stream>>>(xbcf, pcf, P);
    k_scan_v3<<<CH, 256, 0, stream>>>(pcf, dtbf, P, ysf);
    k_gate_v2<<<CH * 128, 256, 0, stream>>>(ysf, zf, P, ynf);
    k_gemm2<<<dim3(8, CH * 8), 256, 0, stream>>>(ynf, outwf, out, s0 * 128);
  }
}

// Round 2
// 2123.305 us; speedup vs baseline: 2.3718x; 1.5238x over previous
//
#include <hip/hip_runtime.h>
#include <math.h>

// B=8, C=128, H=128, W=128, D_INNER=256, D_STATE=64, HEADDIM=32, NHEADS=8,
// D_CONV=4, GN_GROUPS=8, D_XBC=384, D_INPROJ=648.
// Inputs f32 (probed via gn_g word0). OUTPUT IS F32 (reference output dtype).
// d_out = [out_2d: 16,777,216 f32][offset: 131,072 f32].
// h1 (f32) is staged in d_out's out_2d region (written by dwconv, read by gn_off,
// later fully overwritten by gemm2).
//
// R1: scan de-spilled (full unroll) -> 3236us. R2: register-blocked GEMMs
// (BM=256,BN=64,BK=32, 8x8/thread, k-major LDS, float4 frags) replacing the
// 1-output/thread VALU GEMMs; conv1d+gate made in-place to shrink chunk
// footprint (856kB -> 528kB per seq).

__device__ __forceinline__ float b2f(unsigned short u) {
  return __uint_as_float(((unsigned int)u) << 16);
}
__device__ __forceinline__ unsigned short f2b(float f) {
  unsigned int u = __float_as_uint(f);
  unsigned int r = (u + 0x7FFFu + ((u >> 16) & 1u)) >> 16;  // RNE
  return (unsigned short)r;
}
__device__ __forceinline__ bool in_is_f32(const void* gng) {
  return ((const unsigned int*)gng)[0] == 0x3F800000u;
}

#define P_DWW 0
#define P_CW 3200
#define P_CB 4736
#define P_GNG 5120
#define P_GNB 5248
#define P_PWW 5376
#define P_PWB 5504
#define P_DTB 5505
#define P_ALOG 5513
#define P_DSKIP 5521
#define P_NG 5529

__global__ void k_prep_params(const void* dww, const void* cw, const void* cb,
                              const void* gng, const void* gnb, const void* pww,
                              const void* pwb, const void* dtbias, const void* alog,
                              const void* dskip, const void* ng, float* __restrict__ P,
                              float* __restrict__ gst) {
  bool f = in_is_f32(gng);
  int tid = threadIdx.x;
  if (tid < 128) gst[tid] = 0.f;
  auto cvt = [&](const void* src, int n, int off) {
    for (int i = tid; i < n; i += 256)
      P[off + i] = f ? ((const float*)src)[i] : b2f(((const unsigned short*)src)[i]);
  };
  cvt(dww, 3200, P_DWW);
  cvt(cw, 1536, P_CW);
  cvt(cb, 384, P_CB);
  cvt(gng, 128, P_GNG);
  cvt(gnb, 128, P_GNB);
  cvt(pww, 128, P_PWW);
  cvt(pwb, 1, P_PWB);
  cvt(dtbias, 8, P_DTB);
  cvt(alog, 8, P_ALOG);
  cvt(dskip, 8, P_DSKIP);
  cvt(ng, 256, P_NG);
}

__global__ void k_prep_w(const void* wproj, const void* outw, const void* gng,
                         float* __restrict__ wprojf, float* __restrict__ outwf) {
  bool f = in_is_f32(gng);
  int stride = gridDim.x * blockDim.x;
  for (int i = blockIdx.x * blockDim.x + threadIdx.x; i < 82944; i += stride)
    wprojf[i] = f ? ((const float*)wproj)[i] : b2f(((const unsigned short*)wproj)[i]);
  for (int i = blockIdx.x * blockDim.x + threadIdx.x; i < 32768; i += stride)
    outwf[i] = f ? ((const float*)outw)[i] : b2f(((const unsigned short*)outw)[i]);
}

// ---------------- K1: depthwise 5x5 conv (SAME, zero pad) + group stats ----------
__global__ __launch_bounds__(256) void k_dwconv(const void* __restrict__ x,
                                                const void* __restrict__ gng,
                                                const float* __restrict__ P,
                                                float* __restrict__ h1,
                                                float* __restrict__ gst) {
  int bc = blockIdx.x;
  int b = bc >> 7, c = bc & 127;
  bool f32x = in_is_f32(gng);
  __shared__ unsigned short t[132 * 132];
  __shared__ float red[8];
  for (int i = threadIdx.x; i < 132 * 132; i += 256) t[i] = 0;
  __syncthreads();
  const float* xf = (const float*)x + (size_t)bc * 16384;
  const unsigned short* xb = (const unsigned short*)x + (size_t)bc * 16384;
  for (int i = threadIdx.x; i < 16384; i += 256) {
    int y = i >> 7, xw = i & 127;
    t[(y + 2) * 132 + xw + 2] = f32x ? f2b(xf[i]) : xb[i];
  }
  float w[25];
#pragma unroll
  for (int k = 0; k < 25; ++k) w[k] = P[P_DWW + c * 25 + k];
  __syncthreads();
  float s = 0.f, sq = 0.f;
  for (int i = threadIdx.x; i < 16384; i += 256) {
    int y = i >> 7, xw = i & 127;
    float acc = 0.f;
#pragma unroll
    for (int ky = 0; ky < 5; ++ky)
#pragma unroll
      for (int kx = 0; kx < 5; ++kx)
        acc += w[ky * 5 + kx] * b2f(t[(y + ky) * 132 + xw + kx]);
    h1[(size_t)bc * 16384 + i] = acc;
    s += acc; sq += acc * acc;
  }
  for (int o = 32; o; o >>= 1) { s += __shfl_down(s, o, 64); sq += __shfl_down(sq, o, 64); }
  int wv = threadIdx.x >> 6;
  if ((threadIdx.x & 63) == 0) { red[wv] = s; red[4 + wv] = sq; }
  __syncthreads();
  if (threadIdx.x == 0) {
    float ts = red[0] + red[1] + red[2] + red[3];
    float tq = red[4] + red[5] + red[6] + red[7];
    int g = (b << 3) + (c >> 4);
    atomicAdd(&gst[g * 2], ts);
    atomicAdd(&gst[g * 2 + 1], tq);
  }
}

__global__ void k_stats(const float* __restrict__ gst, float* __restrict__ mr) {
  int g = threadIdx.x;
  if (g < 64) {
    const float invN = 1.f / 262144.f;
    float mean = gst[g * 2] * invN;
    float var = gst[g * 2 + 1] * invN - mean * mean;
    mr[g * 2] = mean;
    mr[g * 2 + 1] = rsqrtf(var + 1e-5f);
  }
}

// ---------------- K3: GN + exact GELU + 1x1 conv + tanh*8 -> offset (f32 out) ----
__global__ __launch_bounds__(128) void k_gn_off(const float* __restrict__ h1,
                                                const float* __restrict__ mr,
                                                const float* __restrict__ P,
                                                float* __restrict__ offf,
                                                float* __restrict__ dout) {
  int bh = blockIdx.x;
  int b = bh >> 7, h = bh & 127;
  int w = threadIdx.x;
  float acc = 0.f;
  for (int c = 0; c < 128; ++c) {
    float v = h1[(((size_t)(b * 128 + c)) * 128 + h) * 128 + w];
    int g = b * 8 + (c >> 4);
    float nv = (v - mr[g * 2]) * mr[g * 2 + 1] * P[P_GNG + c] + P[P_GNB + c];
    float ge = 0.5f * nv * (1.f + erff(nv * 0.70710678118f));
    acc += ge * P[P_PWW + c];
  }
  float off = acc + P[P_PWB];
  float ofv = tanhf(off) * 8.0f;
  offf[bh * 128 + w] = ofv;
  dout[16777216 + bh * 128 + w] = ofv;
}

// ---------------- K4: y-only grid sample + transpose -> seq f32 (l,c) ------------
__global__ __launch_bounds__(128) void k_deform(const void* __restrict__ x,
                                                const void* __restrict__ gng,
                                                const float* __restrict__ offf,
                                                float* __restrict__ seqc,
                                                int s0) {
  int bh = s0 + blockIdx.x;
  int b = bh >> 7, h = bh & 127;
  int w = threadIdx.x;
  bool f32x = in_is_f32(gng);
  __shared__ float t[128 * 130];
  float ofv = offf[bh * 128 + w];
  float gy = -1.f + (2.f / 127.f) * (float)h + ofv * (2.f / 127.f);
  gy = fminf(fmaxf(gy, -1.f), 1.f);
  float py = (gy + 1.f) * 0.5f * 127.f;
  py = fminf(fmaxf(py, 0.f), 127.f);
  float y0f = floorf(py);
  float wy = py - y0f;
  int y0 = (int)y0f;
  int y1 = min(y0 + 1, 127);
  const float* xfb = (const float*)x + (size_t)b * 128 * 16384;
  const unsigned short* xbb = (const unsigned short*)x + (size_t)b * 128 * 16384;
  for (int c = 0; c < 128; ++c) {
    size_t o0 = (size_t)c * 16384 + y0 * 128 + w;
    size_t o1 = (size_t)c * 16384 + y1 * 128 + w;
    float v0, v1;
    if (f32x) { v0 = xfb[o0]; v1 = xfb[o1]; }
    else      { v0 = b2f(xbb[o0]); v1 = b2f(xbb[o1]); }
    t[c * 130 + w] = v0 + wy * (v1 - v0);
  }
  __syncthreads();
  int c = threadIdx.x;
  float* sp = seqc + (size_t)blockIdx.x * 16384;
  for (int l = 0; l < 128; ++l) sp[l * 128 + c] = t[c * 130 + l];
}

// ---------------- G1 v2: zxbcdt = seq @ wproj^T --------------------------------
// BM=256 (tokens) x BN=64 (features), BK=32, 256 thr, 8x8 micro-tile.
// LDS k-major: As[kk][m] (stride 260), Bs[kk][e] (stride 68) -> float4 frags,
// <=2-way bank aliasing on reads/writes (free). N blocks: 11*64=704 >= 648.
__global__ __launch_bounds__(256) void k_gemm1_v2(const float* __restrict__ seqp,
                                                  const float* __restrict__ wproj,
                                                  const float* __restrict__ P,
                                                  float* __restrict__ z,
                                                  float* __restrict__ xbc,
                                                  float* __restrict__ dtb,
                                                  int M) {
  __shared__ float As[32][260];
  __shared__ float Bs[32][68];
  int m0 = blockIdx.x * 256;
  int e0 = blockIdx.y * 64;
  int tid = threadIdx.x;
  int tm = tid >> 3;   // 0..31 -> 8 tokens each
  int tn = tid & 7;    // 0..7  -> 8 features each
  float acc[8][8];
#pragma unroll
  for (int r = 0; r < 8; ++r)
#pragma unroll
    for (int j = 0; j < 8; ++j) acc[r][j] = 0.f;

  for (int k0 = 0; k0 < 128; k0 += 32) {
    // stage A: 256 rows x 32 k (2048 float4s -> 8/thread)
#pragma unroll
    for (int t = 0; t < 8; ++t) {
      int i = tid + 256 * t;
      int row = i >> 3, q = i & 7;
      int m = m0 + row; if (m >= M) m = M - 1;
      float4 v = *(const float4*)(seqp + (size_t)m * 128 + k0 + q * 4);
      As[q * 4 + 0][row] = v.x;
      As[q * 4 + 1][row] = v.y;
      As[q * 4 + 2][row] = v.z;
      As[q * 4 + 3][row] = v.w;
    }
    // stage B: 64 rows x 32 k (512 float4s -> 2/thread)
#pragma unroll
    for (int t = 0; t < 2; ++t) {
      int i = tid + 256 * t;
      int row = i >> 3, q = i & 7;
      int e = e0 + row;
      float4 v = make_float4(0.f, 0.f, 0.f, 0.f);
      if (e < 648) v = *(const float4*)(wproj + (size_t)e * 128 + k0 + q * 4);
      Bs[q * 4 + 0][row] = v.x;
      Bs[q * 4 + 1][row] = v.y;
      Bs[q * 4 + 2][row] = v.z;
      Bs[q * 4 + 3][row] = v.w;
    }
    __syncthreads();
#pragma unroll
    for (int kk = 0; kk < 32; ++kk) {
      float4 a0 = *(const float4*)&As[kk][tm * 8];
      float4 a1 = *(const float4*)&As[kk][tm * 8 + 4];
      float4 b0 = *(const float4*)&Bs[kk][tn * 8];
      float4 b1 = *(const float4*)&Bs[kk][tn * 8 + 4];
      float a[8] = {a0.x, a0.y, a0.z, a0.w, a1.x, a1.y, a1.z, a1.w};
      float bb[8] = {b0.x, b0.y, b0.z, b0.w, b1.x, b1.y, b1.z, b1.w};
#pragma unroll
      for (int r = 0; r < 8; ++r)
#pragma unroll
        for (int j = 0; j < 8; ++j) acc[r][j] += a[r] * bb[j];
    }
    __syncthreads();
  }

  int mb = m0 + tm * 8;
  if (e0 < 256) {
    float* p0 = z + (size_t)mb * 256 + e0 + tn * 8;
#pragma unroll
    for (int r = 0; r < 8; ++r) {
      if (mb + r < M) {
        *(float4*)(p0 + (size_t)r * 256) = make_float4(acc[r][0], acc[r][1], acc[r][2], acc[r][3]);
        *(float4*)(p0 + (size_t)r * 256 + 4) = make_float4(acc[r][4], acc[r][5], acc[r][6], acc[r][7]);
      }
    }
  } else if (e0 < 640) {
    float* p0 = xbc + (size_t)mb * 384 + (e0 - 256) + tn * 8;
#pragma unroll
    for (int r = 0; r < 8; ++r) {
      if (mb + r < M) {
        *(float4*)(p0 + (size_t)r * 384) = make_float4(acc[r][0], acc[r][1], acc[r][2], acc[r][3]);
        *(float4*)(p0 + (size_t)r * 384 + 4) = make_float4(acc[r][4], acc[r][5], acc[r][6], acc[r][7]);
      }
    }
  } else if (tn == 0) {
#pragma unroll
    for (int r = 0; r < 8; ++r) {
      if (mb + r < M) {
#pragma unroll
        for (int j = 0; j < 8; ++j) {
          float dv = acc[r][j] + P[P_DTB + j];
          float sp = (dv > 20.f) ? dv : log1pf(__expf(dv));
          dtb[(size_t)(mb + r) * 8 + j] = sp;
        }
      }
    }
  }
}

// ---------------- K5: causal conv1d + SiLU, IN-PLACE on xbc ---------------------
// Safe: each (l,e) is read exactly once (by its own thread) before being written.
__global__ __launch_bounds__(256) void k_conv1d_v3(float* xbc,
                                                   const float* __restrict__ P) {
  float* buf = xbc + (size_t)blockIdx.x * 49152;   // 128*384
  for (int e = threadIdx.x; e < 384; e += 256) {
    float w0 = P[P_CW + e * 4 + 0], w1 = P[P_CW + e * 4 + 1];
    float w2 = P[P_CW + e * 4 + 2], w3 = P[P_CW + e * 4 + 3];
    float bb = P[P_CB + e];
    float x0 = 0.f, x1 = 0.f, x2 = 0.f;
    for (int l = 0; l < 128; ++l) {
      float x3 = buf[l * 384 + e];
      float a = bb + w0 * x0 + w1 * x1 + w2 * x2 + w3 * x3;
      buf[l * 384 + e] = a / (1.f + __expf(-a));
      x0 = x1; x1 = x2; x2 = x3;
    }
  }
}

// ---------------- K6: selective scan v3. block=seq; thread=(head,d) --------------
__global__ __launch_bounds__(256) void k_scan_v3(const float* __restrict__ pc,
                                                 const float* __restrict__ dtb,
                                                 const float* __restrict__ P,
                                                 float* __restrict__ ys) {
  int seq = blockIdx.x;
  int head = threadIdx.x >> 5;    // 0..7
  int d = threadIdx.x & 31;       // 0..31
  float A = -__expf(P[P_ALOG + head]);
  float Dk = P[P_DSKIP + head];
  float h[64];
#pragma unroll
  for (int s = 0; s < 64; ++s) h[s] = 0.f;
  const float* base = pc + (size_t)seq * 49152;
  const float* dtp = dtb + (size_t)seq * 1024;
  float* yp = ys + (size_t)seq * 32768;
  for (int l = 0; l < 128; ++l) {
    const float* rb = base + l * 384;
    float dt = dtp[l * 8 + head];
    float xv = rb[head * 32 + d];
    float dA = __expf(dt * A);
    float coef = dt * xv;
    const float4* Bv = (const float4*)(rb + 256);  // 16B-aligned, wave-uniform
    const float4* Cv = (const float4*)(rb + 320);
    float a0 = 0.f, a1 = 0.f, a2 = 0.f, a3 = 0.f;
#pragma unroll
    for (int q = 0; q < 16; ++q) {
      float4 bq = Bv[q];
      float4 cq = Cv[q];
      h[q * 4 + 0] = h[q * 4 + 0] * dA + coef * bq.x;  a0 += h[q * 4 + 0] * cq.x;
      h[q * 4 + 1] = h[q * 4 + 1] * dA + coef * bq.y;  a1 += h[q * 4 + 1] * cq.y;
      h[q * 4 + 2] = h[q * 4 + 2] * dA + coef * bq.z;  a2 += h[q * 4 + 2] * cq.z;
      h[q * 4 + 3] = h[q * 4 + 3] * dA + coef * bq.w;  a3 += h[q * 4 + 3] * cq.w;
    }
    yp[l * 256 + head * 32 + d] = ((a0 + a1) + (a2 + a3)) + Dk * xv;
  }
}

// ---------------- K7: gate + RMS norm, IN-PLACE on ys ---------------------------
__global__ __launch_bounds__(256) void k_gate_v3(float* ys,
                                                 const float* __restrict__ z,
                                                 const float* __restrict__ P) {
  int l = blockIdx.x;
  int e = threadIdx.x;
  __shared__ float red[4];
  float yv = ys[(size_t)l * 256 + e];
  float zv = z[(size_t)l * 256 + e];
  float g = zv / (1.f + __expf(-zv));
  float y = yv * g;
  float ss = y * y;
  for (int o = 32; o; o >>= 1) ss += __shfl_down(ss, o, 64);
  if ((threadIdx.x & 63) == 0) red[threadIdx.x >> 6] = ss;
  __syncthreads();
  float tot = red[0] + red[1] + red[2] + red[3];
  float r = rsqrtf(tot * (1.f / 256.f) + 1e-5f);
  ys[(size_t)l * 256 + e] = y * r * P[P_NG + e];
}

// ---------------- G2 v2: out GEMM, BM=256 x BN=64, K=256, 8x8/thread ------------
// Output NCHW: channel rows are token-contiguous -> float4 stores.
__global__ __launch_bounds__(256) void k_gemm2_v2(const float* __restrict__ ynorm,
                                                  const float* __restrict__ outw,
                                                  float* __restrict__ dout,
                                                  int tok0, int M) {
  __shared__ float As[32][260];
  __shared__ float Bs[32][68];
  int m0 = blockIdx.x * 256;
  int c0 = blockIdx.y * 64;
  int tid = threadIdx.x;
  int tm = tid >> 3;
  int tn = tid & 7;
  float acc[8][8];
#pragma unroll
  for (int r = 0; r < 8; ++r)
#pragma unroll
    for (int j = 0; j < 8; ++j) acc[r][j] = 0.f;

  for (int k0 = 0; k0 < 256; k0 += 32) {
#pragma unroll
    for (int t = 0; t < 8; ++t) {
      int i = tid + 256 * t;
      int row = i >> 3, q = i & 7;
      int m = m0 + row; if (m >= M) m = M - 1;
      float4 v = *(const float4*)(ynorm + (size_t)m * 256 + k0 + q * 4);
      As[q * 4 + 0][row] = v.x;
      As[q * 4 + 1][row] = v.y;
      As[q * 4 + 2][row] = v.z;
      As[q * 4 + 3][row] = v.w;
    }
#pragma unroll
    for (int t = 0; t < 2; ++t) {
      int i = tid + 256 * t;
      int row = i >> 3, q = i & 7;
      float4 v = *(const float4*)(outw + (size_t)(c0 + row) * 256 + k0 + q * 4);
      Bs[q * 4 + 0][row] = v.x;
      Bs[q * 4 + 1][row] = v.y;
      Bs[q * 4 + 2][row] = v.z;
      Bs[q * 4 + 3][row] = v.w;
    }
    __syncthreads();
#pragma unroll
    for (int kk = 0; kk < 32; ++kk) {
      float4 a0 = *(const float4*)&As[kk][tm * 8];
      float4 a1 = *(const float4*)&As[kk][tm * 8 + 4];
      float4 b0 = *(const float4*)&Bs[kk][tn * 8];
      float4 b1 = *(const float4*)&Bs[kk][tn * 8 + 4];
      float a[8] = {a0.x, a0.y, a0.z, a0.w, a1.x, a1.y, a1.z, a1.w};
      float bb[8] = {b0.x, b0.y, b0.z, b0.w, b1.x, b1.y, b1.z, b1.w};
#pragma unroll
      for (int r = 0; r < 8; ++r)
#pragma unroll
        for (int j = 0; j < 8; ++j) acc[r][j] += a[r] * bb[j];
    }
    __syncthreads();
  }

  // tokens l0..l0+7 are consecutive, within one b (tiles are 256-aligned).
  int mb = m0 + tm * 8;
  int l0 = tok0 + mb;
  int b = l0 >> 14;
  int rem = l0 & 16383;
  if (mb + 7 < M) {
#pragma unroll
    for (int j = 0; j < 8; ++j) {
      int cc = c0 + tn * 8 + j;
      float* dst = dout + (size_t)(b * 128 + cc) * 16384 + rem;
      *(float4*)dst = make_float4(acc[0][j], acc[1][j], acc[2][j], acc[3][j]);
      *(float4*)(dst + 4) = make_float4(acc[4][j], acc[5][j], acc[6][j], acc[7][j]);
    }
  } else {
#pragma unroll
    for (int j = 0; j < 8; ++j) {
      int cc = c0 + tn * 8 + j;
      for (int r = 0; r < 8; ++r) {
        if (mb + r < M) {
          int l = l0 + r;
          dout[(size_t)((l >> 14) * 128 + cc) * 16384 + (l & 16383)] = acc[r][j];
        }
      }
    }
  }
}

extern "C" void kernel_launch(void* const* d_in, const int* in_sizes, int n_in,
                              void* d_out, int out_size, void* d_ws, size_t ws_size,
                              hipStream_t stream) {
  const void* x      = d_in[0];
  const void* dww    = d_in[1];
  const void* gng    = d_in[2];
  const void* gnb    = d_in[3];
  const void* pww    = d_in[4];
  const void* pwb    = d_in[5];
  const void* wproj  = d_in[6];
  const void* cw     = d_in[7];
  const void* cb     = d_in[8];
  const void* dtbias = d_in[9];
  const void* alog   = d_in[10];
  const void* dskip  = d_in[11];
  const void* ng     = d_in[12];
  const void* outw   = d_in[13];
  float* out = (float*)d_out;

  // ws layout (bytes):
  //   0        gst (512)
  //   4096     mr (512)
  //   8192     P (32768)        -> 40960
  //   40960    wprojf (331776)  -> 372736
  //   372736   outwf (131072)   -> 503808
  //   503808   offf (524288)    -> 1028096
  //   1028096  chunk buffers
  char* ws = (char*)d_ws;
  float* gst    = (float*)(ws + 0);
  float* mr     = (float*)(ws + 4096);
  float* P      = (float*)(ws + 8192);
  float* wprojf = (float*)(ws + 40960);
  float* outwf  = (float*)(ws + 372736);
  float* offf   = (float*)(ws + 503808);
  char* cbase   = ws + 1028096;

  // h1 (f32, 67,108,864 B) lives in d_out's out_2d region.
  float* h1f = out;

  // Per-sequence chunk bytes (conv1d in-place on xbc; gate in-place on ys):
  //   seq 65536 + z 131072 + xbc 196608 + dtb 4096 + ys 131072 = 528384.
  const int opts[11] = {1024, 512, 256, 128, 64, 32, 16, 8, 4, 2, 1};
  int CH = 1;
  for (int i = 0; i < 11; ++i) {
    if (1028096ull + (unsigned long long)opts[i] * 528384ull <= (unsigned long long)ws_size) {
      CH = opts[i];
      break;
    }
  }
  int NC = 1024 / CH;

  float* seqf = (float*)(cbase);
  float* zf   = (float*)(cbase + (size_t)CH * 65536);
  float* xbcf = (float*)(cbase + (size_t)CH * 196608);
  float* dtbf = (float*)(cbase + (size_t)CH * 393216);
  float* ysf  = (float*)(cbase + (size_t)CH * 397312);

  k_prep_params<<<1, 256, 0, stream>>>(dww, cw, cb, gng, gnb, pww, pwb, dtbias,
                                       alog, dskip, ng, P, gst);
  k_prep_w<<<128, 256, 0, stream>>>(wproj, outw, gng, wprojf, outwf);
  k_dwconv<<<1024, 256, 0, stream>>>(x, gng, P, h1f, gst);
  k_stats<<<1, 64, 0, stream>>>(gst, mr);
  k_gn_off<<<1024, 128, 0, stream>>>(h1f, mr, P, offf, out);

  int M = CH * 128;
  int mblk = (M + 255) / 256;
  for (int c = 0; c < NC; ++c) {
    int s0 = c * CH;
    k_deform<<<CH, 128, 0, stream>>>(x, gng, offf, seqf, s0);
    k_gemm1_v2<<<dim3(mblk, 11), 256, 0, stream>>>(seqf, wprojf, P, zf, xbcf, dtbf, M);
    k_conv1d_v3<<<CH, 256, 0, stream>>>(xbcf, P);
    k_scan_v3<<<CH, 256, 0, stream>>>(xbcf, dtbf, P, ysf);
    k_gate_v3<<<CH * 128, 256, 0, stream>>>(ysf, zf, P);
    k_gemm2_v2<<<dim3(mblk, 2), 256, 0, stream>>>(ysf, outwf, out, s0 * 128, M);
  }
}

// Round 3
// 1077.861 us; speedup vs baseline: 4.6722x; 1.9699x over previous
//
#include <hip/hip_runtime.h>
#include <math.h>

// B=8, C=128, H=128, W=128, D_INNER=256, D_STATE=64, HEADDIM=32, NHEADS=8,
// D_CONV=4, GN_GROUPS=8, D_XBC=384, D_INPROJ=648.
// Inputs f32 (probed via gn_g word0). OUTPUT IS F32 (reference output dtype).
// d_out = [out_2d: 16,777,216 f32][offset: 131,072 f32].
// h1 (f32) is staged in d_out's out_2d region.
//
// R1: scan de-spilled -> 3236us. R2: register-blocked VALU GEMMs -> 2123us.
// R3: MFMA f16 GEMMs (v_mfma_f32_16x16x32_f16). seq/ynorm/weights cast to f16
// (rel err 4.9e-4; pipeline already tolerates bf16 staging of x). 64-k panels
// in LDS with ch^(row&7) chunk swizzle -> conflict-free b128 LDS ops.
// gemm2 computes with A=out_w (c rows), B=tokens so D cols = tokens ->
// contiguous NCHW stores. ynorm(f16) reuses dead xbc region.

typedef _Float16 half8 __attribute__((ext_vector_type(8)));
typedef float f32x4 __attribute__((ext_vector_type(4)));

__device__ __forceinline__ float b2f(unsigned short u) {
  return __uint_as_float(((unsigned int)u) << 16);
}
__device__ __forceinline__ unsigned short f2b(float f) {
  unsigned int u = __float_as_uint(f);
  unsigned int r = (u + 0x7FFFu + ((u >> 16) & 1u)) >> 16;  // RNE
  return (unsigned short)r;
}
__device__ __forceinline__ bool in_is_f32(const void* gng) {
  return ((const unsigned int*)gng)[0] == 0x3F800000u;
}

#define P_DWW 0
#define P_CW 3200
#define P_CB 4736
#define P_GNG 5120
#define P_GNB 5248
#define P_PWW 5376
#define P_PWB 5504
#define P_DTB 5505
#define P_ALOG 5513
#define P_DSKIP 5521
#define P_NG 5529

__global__ void k_prep_params(const void* dww, const void* cw, const void* cb,
                              const void* gng, const void* gnb, const void* pww,
                              const void* pwb, const void* dtbias, const void* alog,
                              const void* dskip, const void* ng, float* __restrict__ P,
                              float* __restrict__ gst) {
  bool f = in_is_f32(gng);
  int tid = threadIdx.x;
  if (tid < 128) gst[tid] = 0.f;
  auto cvt = [&](const void* src, int n, int off) {
    for (int i = tid; i < n; i += 256)
      P[off + i] = f ? ((const float*)src)[i] : b2f(((const unsigned short*)src)[i]);
  };
  cvt(dww, 3200, P_DWW);
  cvt(cw, 1536, P_CW);
  cvt(cb, 384, P_CB);
  cvt(gng, 128, P_GNG);
  cvt(gnb, 128, P_GNB);
  cvt(pww, 128, P_PWW);
  cvt(pwb, 1, P_PWB);
  cvt(dtbias, 8, P_DTB);
  cvt(alog, 8, P_ALOG);
  cvt(dskip, 8, P_DSKIP);
  cvt(ng, 256, P_NG);
}

// wprojh: 768 x 128 f16 (rows >=648 zero).  outwh: 128 x 256 f16.
__global__ void k_prep_w(const void* wproj, const void* outw, const void* gng,
                         _Float16* __restrict__ wprojh, _Float16* __restrict__ outwh) {
  bool f = in_is_f32(gng);
  int stride = gridDim.x * blockDim.x;
  for (int i = blockIdx.x * blockDim.x + threadIdx.x; i < 98304; i += stride) {
    int row = i >> 7;
    float v = 0.f;
    if (row < 648) v = f ? ((const float*)wproj)[i] : b2f(((const unsigned short*)wproj)[i]);
    wprojh[i] = (_Float16)v;
  }
  for (int i = blockIdx.x * blockDim.x + threadIdx.x; i < 32768; i += stride)
    outwh[i] = (_Float16)(f ? ((const float*)outw)[i] : b2f(((const unsigned short*)outw)[i]));
}

// ---------------- K1: depthwise 5x5 conv (SAME, zero pad) + group stats ----------
__global__ __launch_bounds__(256) void k_dwconv(const void* __restrict__ x,
                                                const void* __restrict__ gng,
                                                const float* __restrict__ P,
                                                float* __restrict__ h1,
                                                float* __restrict__ gst) {
  int bc = blockIdx.x;
  int b = bc >> 7, c = bc & 127;
  bool f32x = in_is_f32(gng);
  __shared__ unsigned short t[132 * 132];
  __shared__ float red[8];
  for (int i = threadIdx.x; i < 132 * 132; i += 256) t[i] = 0;
  __syncthreads();
  const float* xf = (const float*)x + (size_t)bc * 16384;
  const unsigned short* xb = (const unsigned short*)x + (size_t)bc * 16384;
  for (int i = threadIdx.x; i < 16384; i += 256) {
    int y = i >> 7, xw = i & 127;
    t[(y + 2) * 132 + xw + 2] = f32x ? f2b(xf[i]) : xb[i];
  }
  float w[25];
#pragma unroll
  for (int k = 0; k < 25; ++k) w[k] = P[P_DWW + c * 25 + k];
  __syncthreads();
  float s = 0.f, sq = 0.f;
  for (int i = threadIdx.x; i < 16384; i += 256) {
    int y = i >> 7, xw = i & 127;
    float acc = 0.f;
#pragma unroll
    for (int ky = 0; ky < 5; ++ky)
#pragma unroll
      for (int kx = 0; kx < 5; ++kx)
        acc += w[ky * 5 + kx] * b2f(t[(y + ky) * 132 + xw + kx]);
    h1[(size_t)bc * 16384 + i] = acc;
    s += acc; sq += acc * acc;
  }
  for (int o = 32; o; o >>= 1) { s += __shfl_down(s, o, 64); sq += __shfl_down(sq, o, 64); }
  int wv = threadIdx.x >> 6;
  if ((threadIdx.x & 63) == 0) { red[wv] = s; red[4 + wv] = sq; }
  __syncthreads();
  if (threadIdx.x == 0) {
    float ts = red[0] + red[1] + red[2] + red[3];
    float tq = red[4] + red[5] + red[6] + red[7];
    int g = (b << 3) + (c >> 4);
    atomicAdd(&gst[g * 2], ts);
    atomicAdd(&gst[g * 2 + 1], tq);
  }
}

__global__ void k_stats(const float* __restrict__ gst, float* __restrict__ mr) {
  int g = threadIdx.x;
  if (g < 64) {
    const float invN = 1.f / 262144.f;
    float mean = gst[g * 2] * invN;
    float var = gst[g * 2 + 1] * invN - mean * mean;
    mr[g * 2] = mean;
    mr[g * 2 + 1] = rsqrtf(var + 1e-5f);
  }
}

// ---------------- K3: GN + exact GELU + 1x1 conv + tanh*8 -> offset (f32 out) ----
__global__ __launch_bounds__(128) void k_gn_off(const float* __restrict__ h1,
                                                const float* __restrict__ mr,
                                                const float* __restrict__ P,
                                                float* __restrict__ offf,
                                                float* __restrict__ dout) {
  int bh = blockIdx.x;
  int b = bh >> 7, h = bh & 127;
  int w = threadIdx.x;
  float acc = 0.f;
  for (int c = 0; c < 128; ++c) {
    float v = h1[(((size_t)(b * 128 + c)) * 128 + h) * 128 + w];
    int g = b * 8 + (c >> 4);
    float nv = (v - mr[g * 2]) * mr[g * 2 + 1] * P[P_GNG + c] + P[P_GNB + c];
    float ge = 0.5f * nv * (1.f + erff(nv * 0.70710678118f));
    acc += ge * P[P_PWW + c];
  }
  float off = acc + P[P_PWB];
  float ofv = tanhf(off) * 8.0f;
  offf[bh * 128 + w] = ofv;
  dout[16777216 + bh * 128 + w] = ofv;
}

// ---------------- K4: y-only grid sample + transpose -> seq f16 (l,c) ------------
__global__ __launch_bounds__(128) void k_deform(const void* __restrict__ x,
                                                const void* __restrict__ gng,
                                                const float* __restrict__ offf,
                                                _Float16* __restrict__ seqc,
                                                int s0) {
  int bh = s0 + blockIdx.x;
  int b = bh >> 7, h = bh & 127;
  int w = threadIdx.x;
  bool f32x = in_is_f32(gng);
  __shared__ float t[128 * 130];
  float ofv = offf[bh * 128 + w];
  float gy = -1.f + (2.f / 127.f) * (float)h + ofv * (2.f / 127.f);
  gy = fminf(fmaxf(gy, -1.f), 1.f);
  float py = (gy + 1.f) * 0.5f * 127.f;
  py = fminf(fmaxf(py, 0.f), 127.f);
  float y0f = floorf(py);
  float wy = py - y0f;
  int y0 = (int)y0f;
  int y1 = min(y0 + 1, 127);
  const float* xfb = (const float*)x + (size_t)b * 128 * 16384;
  const unsigned short* xbb = (const unsigned short*)x + (size_t)b * 128 * 16384;
  for (int c = 0; c < 128; ++c) {
    size_t o0 = (size_t)c * 16384 + y0 * 128 + w;
    size_t o1 = (size_t)c * 16384 + y1 * 128 + w;
    float v0, v1;
    if (f32x) { v0 = xfb[o0]; v1 = xfb[o1]; }
    else      { v0 = b2f(xbb[o0]); v1 = b2f(xbb[o1]); }
    t[c * 130 + w] = v0 + wy * (v1 - v0);
  }
  __syncthreads();
  int c = threadIdx.x;
  _Float16* sp = seqc + (size_t)blockIdx.x * 16384;
  for (int l = 0; l < 128; ++l) sp[l * 128 + c] = (_Float16)t[c * 130 + l];
}

// ---------------- G1 v3: zxbcdt = seq @ wproj^T via MFMA f16 --------------------
// BM=128 tokens x BN=128 e, K staged in 64-wide panels (2 iters).
// LDS layout: [row][64 k] f16, 16B chunks, chunk swizz ch^(row&7) -> conflict-free.
// Frag layouts (m89-verified, dtype-indep): A row=lane&15, k=(lane>>4)*8+j;
// B col=lane&15, k=(lane>>4)*8+j; D col=lane&15, row=(lane>>4)*4+reg.
__global__ __launch_bounds__(256) void k_gemm1_v3(const _Float16* __restrict__ seqh,
                                                  const _Float16* __restrict__ wprojh,
                                                  const float* __restrict__ P,
                                                  float* __restrict__ z,
                                                  float* __restrict__ xbc,
                                                  float* __restrict__ dtb) {
  __shared__ __align__(16) _Float16 lA[128 * 64];
  __shared__ __align__(16) _Float16 lB[128 * 64];
  int m0 = blockIdx.x * 128;
  int e0 = blockIdx.y * 128;
  int tid = threadIdx.x;
  int lane = tid & 63;
  int wv = tid >> 6;
  f32x4 acc[2][8];
#pragma unroll
  for (int rf = 0; rf < 2; ++rf)
#pragma unroll
    for (int cf = 0; cf < 8; ++cf) acc[rf][cf] = (f32x4){0.f, 0.f, 0.f, 0.f};

  int rsel = lane & 15, q = lane >> 4;
  for (int k0 = 0; k0 < 128; k0 += 64) {
    if (k0) __syncthreads();
#pragma unroll
    for (int p = 0; p < 4; ++p) {
      int idx = tid + 256 * p;
      int row = idx >> 3, ch = idx & 7;
      int dch = ch ^ (row & 7);
      *(half8*)&lA[row * 64 + dch * 8] =
          *(const half8*)&seqh[(size_t)(m0 + row) * 128 + k0 + ch * 8];
      *(half8*)&lB[row * 64 + dch * 8] =
          *(const half8*)&wprojh[(size_t)(e0 + row) * 128 + k0 + ch * 8];
    }
    __syncthreads();
#pragma unroll
    for (int kk = 0; kk < 2; ++kk) {
      half8 a[2];
#pragma unroll
      for (int rf = 0; rf < 2; ++rf) {
        int row = wv * 32 + rf * 16 + rsel;
        int ch = (kk * 4 + q) ^ (row & 7);
        a[rf] = *(const half8*)&lA[row * 64 + ch * 8];
      }
#pragma unroll
      for (int cf = 0; cf < 8; ++cf) {
        int row = cf * 16 + rsel;
        int ch = (kk * 4 + q) ^ (row & 7);
        half8 b = *(const half8*)&lB[row * 64 + ch * 8];
        acc[0][cf] = __builtin_amdgcn_mfma_f32_16x16x32_f16(a[0], b, acc[0][cf], 0, 0, 0);
        acc[1][cf] = __builtin_amdgcn_mfma_f32_16x16x32_f16(a[1], b, acc[1][cf], 0, 0, 0);
      }
    }
  }

#pragma unroll
  for (int rf = 0; rf < 2; ++rf) {
    int mb = m0 + wv * 32 + rf * 16 + q * 4;
    if (e0 < 256) {
#pragma unroll
      for (int cf = 0; cf < 8; ++cf) {
        float* pz = z + (size_t)mb * 256 + e0 + cf * 16 + rsel;
#pragma unroll
        for (int r = 0; r < 4; ++r) pz[(size_t)r * 256] = acc[rf][cf][r];
      }
    } else if (e0 < 640) {
#pragma unroll
      for (int cf = 0; cf < 8; ++cf) {
        float* px = xbc + (size_t)mb * 384 + (e0 - 256) + cf * 16 + rsel;
#pragma unroll
        for (int r = 0; r < 4; ++r) px[(size_t)r * 384] = acc[rf][cf][r];
      }
    } else {
      if (rsel < 8) {
        float bias = P[P_DTB + rsel];
#pragma unroll
        for (int r = 0; r < 4; ++r) {
          float dv = acc[rf][0][r] + bias;
          float sp = (dv > 20.f) ? dv : log1pf(__expf(dv));
          dtb[(size_t)(mb + r) * 8 + rsel] = sp;
        }
      }
    }
  }
}

// ---------------- K5: causal conv1d + SiLU, IN-PLACE on xbc ---------------------
__global__ __launch_bounds__(256) void k_conv1d_v3(float* xbc,
                                                   const float* __restrict__ P) {
  float* buf = xbc + (size_t)blockIdx.x * 49152;   // 128*384
  for (int e = threadIdx.x; e < 384; e += 256) {
    float w0 = P[P_CW + e * 4 + 0], w1 = P[P_CW + e * 4 + 1];
    float w2 = P[P_CW + e * 4 + 2], w3 = P[P_CW + e * 4 + 3];
    float bb = P[P_CB + e];
    float x0 = 0.f, x1 = 0.f, x2 = 0.f;
    for (int l = 0; l < 128; ++l) {
      float x3 = buf[l * 384 + e];
      float a = bb + w0 * x0 + w1 * x1 + w2 * x2 + w3 * x3;
      buf[l * 384 + e] = a / (1.f + __expf(-a));
      x0 = x1; x1 = x2; x2 = x3;
    }
  }
}

// ---------------- K6: selective scan. block=seq; thread=(head,d) -----------------
__global__ __launch_bounds__(256) void k_scan_v3(const float* __restrict__ pc,
                                                 const float* __restrict__ dtb,
                                                 const float* __restrict__ P,
                                                 float* __restrict__ ys) {
  int seq = blockIdx.x;
  int head = threadIdx.x >> 5;    // 0..7
  int d = threadIdx.x & 31;       // 0..31
  float A = -__expf(P[P_ALOG + head]);
  float Dk = P[P_DSKIP + head];
  float h[64];
#pragma unroll
  for (int s = 0; s < 64; ++s) h[s] = 0.f;
  const float* base = pc + (size_t)seq * 49152;
  const float* dtp = dtb + (size_t)seq * 1024;
  float* yp = ys + (size_t)seq * 32768;
  for (int l = 0; l < 128; ++l) {
    const float* rb = base + l * 384;
    float dt = dtp[l * 8 + head];
    float xv = rb[head * 32 + d];
    float dA = __expf(dt * A);
    float coef = dt * xv;
    const float4* Bv = (const float4*)(rb + 256);  // 16B-aligned, wave-uniform
    const float4* Cv = (const float4*)(rb + 320);
    float a0 = 0.f, a1 = 0.f, a2 = 0.f, a3 = 0.f;
#pragma unroll
    for (int qq = 0; qq < 16; ++qq) {
      float4 bq = Bv[qq];
      float4 cq = Cv[qq];
      h[qq * 4 + 0] = h[qq * 4 + 0] * dA + coef * bq.x;  a0 += h[qq * 4 + 0] * cq.x;
      h[qq * 4 + 1] = h[qq * 4 + 1] * dA + coef * bq.y;  a1 += h[qq * 4 + 1] * cq.y;
      h[qq * 4 + 2] = h[qq * 4 + 2] * dA + coef * bq.z;  a2 += h[qq * 4 + 2] * cq.z;
      h[qq * 4 + 3] = h[qq * 4 + 3] * dA + coef * bq.w;  a3 += h[qq * 4 + 3] * cq.w;
    }
    yp[l * 256 + head * 32 + d] = ((a0 + a1) + (a2 + a3)) + Dk * xv;
  }
}

// ---------------- K7: gate + RMS norm -> ynorm f16 ------------------------------
__global__ __launch_bounds__(256) void k_gate_v4(const float* __restrict__ ys,
                                                 const float* __restrict__ z,
                                                 const float* __restrict__ P,
                                                 _Float16* __restrict__ ynh) {
  int l = blockIdx.x;
  int e = threadIdx.x;
  __shared__ float red[4];
  float yv = ys[(size_t)l * 256 + e];
  float zv = z[(size_t)l * 256 + e];
  float g = zv / (1.f + __expf(-zv));
  float y = yv * g;
  float ss = y * y;
  for (int o = 32; o; o >>= 1) ss += __shfl_down(ss, o, 64);
  if ((threadIdx.x & 63) == 0) red[threadIdx.x >> 6] = ss;
  __syncthreads();
  float tot = red[0] + red[1] + red[2] + red[3];
  float r = rsqrtf(tot * (1.f / 256.f) + 1e-5f);
  ynh[(size_t)l * 256 + e] = (_Float16)(y * r * P[P_NG + e]);
}

// ---------------- G2 v3: out = ynorm @ outw^T via MFMA f16 ----------------------
// Operands swapped: A = outwh (128 c-rows x 256 k), B = ynorm tokens -> D cols =
// tokens (contiguous NCHW stores). Block: all 128 c x 64 tokens; K in 4 panels.
__global__ __launch_bounds__(256) void k_gemm2_v3(const _Float16* __restrict__ ynh,
                                                  const _Float16* __restrict__ outwh,
                                                  float* __restrict__ dout,
                                                  int tok0) {
  __shared__ __align__(16) _Float16 lA[128 * 64];
  __shared__ __align__(16) _Float16 lB[64 * 64];
  int t0 = blockIdx.x * 64;
  int tid = threadIdx.x;
  int lane = tid & 63;
  int wv = tid >> 6;
  f32x4 acc[2][4];
#pragma unroll
  for (int rf = 0; rf < 2; ++rf)
#pragma unroll
    for (int cf = 0; cf < 4; ++cf) acc[rf][cf] = (f32x4){0.f, 0.f, 0.f, 0.f};

  int rsel = lane & 15, q = lane >> 4;
  for (int k0 = 0; k0 < 256; k0 += 64) {
    if (k0) __syncthreads();
#pragma unroll
    for (int p = 0; p < 4; ++p) {
      int idx = tid + 256 * p;
      int row = idx >> 3, ch = idx & 7;
      int dch = ch ^ (row & 7);
      *(half8*)&lA[row * 64 + dch * 8] =
          *(const half8*)&outwh[(size_t)row * 256 + k0 + ch * 8];
    }
#pragma unroll
    for (int p = 0; p < 2; ++p) {
      int idx = tid + 256 * p;
      int row = idx >> 3, ch = idx & 7;
      int dch = ch ^ (row & 7);
      *(half8*)&lB[row * 64 + dch * 8] =
          *(const half8*)&ynh[(size_t)(t0 + row) * 256 + k0 + ch * 8];
    }
    __syncthreads();
#pragma unroll
    for (int kk = 0; kk < 2; ++kk) {
      half8 a[2];
#pragma unroll
      for (int rf = 0; rf < 2; ++rf) {
        int row = wv * 32 + rf * 16 + rsel;
        int ch = (kk * 4 + q) ^ (row & 7);
        a[rf] = *(const half8*)&lA[row * 64 + ch * 8];
      }
#pragma unroll
      for (int cf = 0; cf < 4; ++cf) {
        int row = cf * 16 + rsel;
        int ch = (kk * 4 + q) ^ (row & 7);
        half8 b = *(const half8*)&lB[row * 64 + ch * 8];
        acc[0][cf] = __builtin_amdgcn_mfma_f32_16x16x32_f16(a[0], b, acc[0][cf], 0, 0, 0);
        acc[1][cf] = __builtin_amdgcn_mfma_f32_16x16x32_f16(a[1], b, acc[1][cf], 0, 0, 0);
      }
    }
  }

  int l0 = tok0 + t0;
  int b = l0 >> 14;
  int rem0 = l0 & 16383;
#pragma unroll
  for (int rf = 0; rf < 2; ++rf) {
    int cbase = wv * 32 + rf * 16 + q * 4;
#pragma unroll
    for (int cf = 0; cf < 4; ++cf) {
#pragma unroll
      for (int r = 0; r < 4; ++r) {
        dout[(size_t)(b * 128 + cbase + r) * 16384 + rem0 + cf * 16 + rsel] = acc[rf][cf][r];
      }
    }
  }
}

extern "C" void kernel_launch(void* const* d_in, const int* in_sizes, int n_in,
                              void* d_out, int out_size, void* d_ws, size_t ws_size,
                              hipStream_t stream) {
  const void* x      = d_in[0];
  const void* dww    = d_in[1];
  const void* gng    = d_in[2];
  const void* gnb    = d_in[3];
  const void* pww    = d_in[4];
  const void* pwb    = d_in[5];
  const void* wproj  = d_in[6];
  const void* cw     = d_in[7];
  const void* cb     = d_in[8];
  const void* dtbias = d_in[9];
  const void* alog   = d_in[10];
  const void* dskip  = d_in[11];
  const void* ng     = d_in[12];
  const void* outw   = d_in[13];
  float* out = (float*)d_out;

  // ws layout (bytes):
  //   0        gst (512)
  //   4096     mr (512)
  //   8192     P (32768)          -> 40960
  //   40960    wprojh f16 (196608)-> 237568
  //   372736   outwh f16 (65536)  -> 438272
  //   503808   offf (524288)      -> 1028096
  //   1028096  chunk buffers
  char* ws = (char*)d_ws;
  float* gst        = (float*)(ws + 0);
  float* mr         = (float*)(ws + 4096);
  float* P          = (float*)(ws + 8192);
  _Float16* wprojh  = (_Float16*)(ws + 40960);
  _Float16* outwh   = (_Float16*)(ws + 372736);
  float* offf       = (float*)(ws + 503808);
  char* cbase       = ws + 1028096;

  // h1 (f32, 67,108,864 B) lives in d_out's out_2d region.
  float* h1f = out;

  // Per-sequence chunk bytes:
  //   seq f16 32768 + z 131072 + xbc 196608 + dtb 4096 + ys 131072 = 495616.
  //   (ynorm f16 reuses xbc region: dead after scan.)
  const int opts[11] = {1024, 512, 256, 128, 64, 32, 16, 8, 4, 2, 1};
  int CH = 1;
  for (int i = 0; i < 11; ++i) {
    if (1028096ull + (unsigned long long)opts[i] * 495616ull <= (unsigned long long)ws_size) {
      CH = opts[i];
      break;
    }
  }
  int NC = 1024 / CH;

  _Float16* seqh = (_Float16*)(cbase);
  float* zf      = (float*)(cbase + (size_t)CH * 32768);
  float* xbcf    = (float*)(cbase + (size_t)CH * 163840);
  float* dtbf    = (float*)(cbase + (size_t)CH * 360448);
  float* ysf     = (float*)(cbase + (size_t)CH * 364544);
  _Float16* ynh  = (_Float16*)xbcf;

  k_prep_params<<<1, 256, 0, stream>>>(dww, cw, cb, gng, gnb, pww, pwb, dtbias,
                                       alog, dskip, ng, P, gst);
  k_prep_w<<<128, 256, 0, stream>>>(wproj, outw, gng, wprojh, outwh);
  k_dwconv<<<1024, 256, 0, stream>>>(x, gng, P, h1f, gst);
  k_stats<<<1, 64, 0, stream>>>(gst, mr);
  k_gn_off<<<1024, 128, 0, stream>>>(h1f, mr, P, offf, out);

  int M = CH * 128;
  for (int c = 0; c < NC; ++c) {
    int s0 = c * CH;
    k_deform<<<CH, 128, 0, stream>>>(x, gng, offf, seqh, s0);
    k_gemm1_v3<<<dim3(M / 128, 6), 256, 0, stream>>>(seqh, wprojh, P, zf, xbcf, dtbf);
    k_conv1d_v3<<<CH, 256, 0, stream>>>(xbcf, P);
    k_scan_v3<<<CH, 256, 0, stream>>>(xbcf, dtbf, P, ysf);
    k_gate_v4<<<CH * 128, 256, 0, stream>>>(ysf, zf, P, ynh);
    k_gemm2_v3<<<dim3(M / 64), 256, 0, stream>>>(ynh, outwh, out, s0 * 128);
  }
}